// Round 2
// baseline (104.517 us; speedup 1.0000x reference)
//
#include <hip/hip_runtime.h>

#define HH 1024
#define WW 1024
#define NB 4
#define RR 8
#define NCH1 13
#define NCH2 4
#define VSEG 8
#define LDSW 1040  // 8 left pad + 1024 + 8 right pad
#define INV_AREA (1.0f/289.0f)
#define EPS_REG 0.01f

typedef float f4 __attribute__((ext_vector_type(4)));

__device__ __forceinline__ int refl(int j, int n) {
    int k = j < 0 ? -j : j;
    return k >= n ? 2 * n - 2 - k : k;
}

__device__ __forceinline__ void derived13(f4 i0, f4 i1, f4 i2, f4 pp, f4* d) {
    d[0] = i0; d[1] = i1; d[2] = i2; d[3] = pp;
    d[4] = i0 * pp; d[5] = i1 * pp; d[6] = i2 * pp;
    d[7] = i0 * i0; d[8] = i0 * i1; d[9] = i0 * i2;
    d[10] = i1 * i1; d[11] = i1 * i2; d[12] = i2 * i2;
}

// Stage 1: vertical sliding sums of 13 derived channels (registers), horizontal
// 17-tap via LDS row with reflect pads, then per-pixel 3x3 solve -> a(3), b(1).
__global__ __launch_bounds__(256, 2) void gf_stage1(
    const float* __restrict__ I, const float* __restrict__ P,
    float* __restrict__ A, float* __restrict__ Bc)
{
    __shared__ float lds[NCH1][LDSW];
    const int tid = threadIdx.x;
    const int y0 = blockIdx.x * VSEG;
    const int bz = blockIdx.y;
    const int c0 = 4 * tid;
    const float* Ib = I + (size_t)bz * 3 * HH * WW;
    const float* Pb = P + (size_t)bz * HH * WW;

    f4 vs[NCH1];
    #pragma unroll
    for (int ch = 0; ch < NCH1; ++ch) { vs[ch] = (f4){0.f, 0.f, 0.f, 0.f}; }

    // warm-up: rows y0-8 .. y0+8 (reflected)
    for (int dy = -RR; dy <= RR; ++dy) {
        int row = refl(y0 + dy, HH);
        size_t rb = (size_t)row * WW + c0;
        f4 i0 = *(const f4*)(Ib + rb);
        f4 i1 = *(const f4*)(Ib + (size_t)HH * WW + rb);
        f4 i2 = *(const f4*)(Ib + (size_t)2 * HH * WW + rb);
        f4 pp = *(const f4*)(Pb + rb);
        f4 d[NCH1]; derived13(i0, i1, i2, pp, d);
        #pragma unroll
        for (int ch = 0; ch < NCH1; ++ch) vs[ch] += d[ch];
    }

    for (int y = y0; y < y0 + VSEG; ++y) {
        // dump vertical sums to LDS (position 8 + col)
        #pragma unroll
        for (int ch = 0; ch < NCH1; ++ch)
            *(f4*)&lds[ch][8 + c0] = vs[ch];
        // reflect pads: pos p (0..7) <- col 8-p ; pos 1032+k <- col 1022-k
        if (tid <= 2) {
            #pragma unroll
            for (int j = 0; j < 4; ++j) {
                int c = c0 + j;
                if (c >= 1 && c <= 8) {
                    #pragma unroll
                    for (int ch = 0; ch < NCH1; ++ch) lds[ch][8 - c] = vs[ch][j];
                }
            }
        }
        if (tid >= 253) {
            #pragma unroll
            for (int j = 0; j < 4; ++j) {
                int c = c0 + j;
                if (c >= 1015 && c <= 1022) {
                    #pragma unroll
                    for (int ch = 0; ch < NCH1; ++ch) lds[ch][1032 + (1022 - c)] = vs[ch][j];
                }
            }
        }
        // prefetch next add/sub rows (stay in flight across the barrier)
        const bool upd = (y + 1 < y0 + VSEG);
        f4 ai0, ai1, ai2, ap, si0, si1, si2, sp;
        if (upd) {
            int ra = refl(y + 1 + RR, HH);
            int rs = refl(y - RR, HH);
            size_t rba = (size_t)ra * WW + c0;
            size_t rbs = (size_t)rs * WW + c0;
            ai0 = *(const f4*)(Ib + rba);
            ai1 = *(const f4*)(Ib + (size_t)HH * WW + rba);
            ai2 = *(const f4*)(Ib + (size_t)2 * HH * WW + rba);
            ap  = *(const f4*)(Pb + rba);
            si0 = *(const f4*)(Ib + rbs);
            si1 = *(const f4*)(Ib + (size_t)HH * WW + rbs);
            si2 = *(const f4*)(Ib + (size_t)2 * HH * WW + rbs);
            sp  = *(const f4*)(Pb + rbs);
        }
        __syncthreads();

        // horizontal 17-tap sliding sums for 4 owned columns
        f4 m[NCH1];
        #pragma unroll
        for (int ch = 0; ch < NCH1; ++ch) {
            float vv[20];
            #pragma unroll
            for (int k = 0; k < 5; ++k)
                ((f4*)vv)[k] = *(const f4*)&lds[ch][c0 + 4 * k];
            float s = (((vv[0]+vv[1])+(vv[2]+vv[3])) + ((vv[4]+vv[5])+(vv[6]+vv[7])))
                    + (((vv[8]+vv[9])+(vv[10]+vv[11])) + ((vv[12]+vv[13])+(vv[14]+vv[15])))
                    + vv[16];
            f4 mm;
            mm[0] = s;
            s += vv[17] - vv[0]; mm[1] = s;
            s += vv[18] - vv[1]; mm[2] = s;
            s += vv[19] - vv[2]; mm[3] = s;
            m[ch] = mm * INV_AREA;
        }

        // per-pixel 3x3 symmetric solve (adjugate)
        f4 oa0, oa1, oa2, ob;
        #pragma unroll
        for (int j = 0; j < 4; ++j) {
            float m0 = m[0][j], m1 = m[1][j], m2 = m[2][j], m3 = m[3][j];
            float r0 = m[4][j] - m0 * m3;
            float r1 = m[5][j] - m1 * m3;
            float r2 = m[6][j] - m2 * m3;
            float S00 = m[7][j]  - m0 * m0 + EPS_REG;
            float S01 = m[8][j]  - m0 * m1;
            float S02 = m[9][j]  - m0 * m2;
            float S11 = m[10][j] - m1 * m1 + EPS_REG;
            float S12 = m[11][j] - m1 * m2;
            float S22 = m[12][j] - m2 * m2 + EPS_REG;
            float A0 = S11 * S22 - S12 * S12;
            float B0 = S02 * S12 - S01 * S22;
            float C0 = S01 * S12 - S02 * S11;
            float D0 = S00 * S22 - S02 * S02;
            float E0 = S01 * S02 - S00 * S12;
            float F0 = S00 * S11 - S01 * S01;
            float det = S00 * A0 + S01 * B0 + S02 * C0;
            float inv = 1.0f / det;
            float a0 = (A0 * r0 + B0 * r1 + C0 * r2) * inv;
            float a1 = (B0 * r0 + D0 * r1 + E0 * r2) * inv;
            float a2 = (C0 * r0 + E0 * r1 + F0 * r2) * inv;
            float bb = m3 - (a0 * m0 + a1 * m1 + a2 * m2);
            oa0[j] = a0; oa1[j] = a1; oa2[j] = a2; ob[j] = bb;
        }
        size_t obase = (size_t)y * WW + c0;
        *(f4*)(A + (size_t)(bz * 3 + 0) * HH * WW + obase) = oa0;
        *(f4*)(A + (size_t)(bz * 3 + 1) * HH * WW + obase) = oa1;
        *(f4*)(A + (size_t)(bz * 3 + 2) * HH * WW + obase) = oa2;
        *(f4*)(Bc + (size_t)bz * HH * WW + obase) = ob;
        __syncthreads();

        if (upd) {
            f4 d[NCH1];
            derived13(ai0, ai1, ai2, ap, d);
            #pragma unroll
            for (int ch = 0; ch < NCH1; ++ch) vs[ch] += d[ch];
            derived13(si0, si1, si2, sp, d);
            #pragma unroll
            for (int ch = 0; ch < NCH1; ++ch) vs[ch] -= d[ch];
        }
    }
}

// Stage 2: box filter a(3),b(1) the same way, then q = mean_a . I + mean_b
__global__ __launch_bounds__(256, 2) void gf_stage2(
    const float* __restrict__ I, const float* __restrict__ A,
    const float* __restrict__ Bc, float* __restrict__ Q)
{
    __shared__ float lds[NCH2][LDSW];
    const int tid = threadIdx.x;
    const int y0 = blockIdx.x * VSEG;
    const int bz = blockIdx.y;
    const int c0 = 4 * tid;
    const float* A0p = A + (size_t)(bz * 3 + 0) * HH * WW;
    const float* A1p = A + (size_t)(bz * 3 + 1) * HH * WW;
    const float* A2p = A + (size_t)(bz * 3 + 2) * HH * WW;
    const float* Bp  = Bc + (size_t)bz * HH * WW;
    const float* Ib  = I + (size_t)bz * 3 * HH * WW;

    f4 vs[NCH2];
    #pragma unroll
    for (int ch = 0; ch < NCH2; ++ch) { vs[ch] = (f4){0.f, 0.f, 0.f, 0.f}; }

    for (int dy = -RR; dy <= RR; ++dy) {
        int row = refl(y0 + dy, HH);
        size_t rb = (size_t)row * WW + c0;
        vs[0] += *(const f4*)(A0p + rb);
        vs[1] += *(const f4*)(A1p + rb);
        vs[2] += *(const f4*)(A2p + rb);
        vs[3] += *(const f4*)(Bp + rb);
    }

    for (int y = y0; y < y0 + VSEG; ++y) {
        #pragma unroll
        for (int ch = 0; ch < NCH2; ++ch)
            *(f4*)&lds[ch][8 + c0] = vs[ch];
        if (tid <= 2) {
            #pragma unroll
            for (int j = 0; j < 4; ++j) {
                int c = c0 + j;
                if (c >= 1 && c <= 8) {
                    #pragma unroll
                    for (int ch = 0; ch < NCH2; ++ch) lds[ch][8 - c] = vs[ch][j];
                }
            }
        }
        if (tid >= 253) {
            #pragma unroll
            for (int j = 0; j < 4; ++j) {
                int c = c0 + j;
                if (c >= 1015 && c <= 1022) {
                    #pragma unroll
                    for (int ch = 0; ch < NCH2; ++ch) lds[ch][1032 + (1022 - c)] = vs[ch][j];
                }
            }
        }
        // prefetch: next add/sub rows of a,b + current I row
        const bool upd = (y + 1 < y0 + VSEG);
        f4 aa0, aa1, aa2, ab, sa0, sa1, sa2, sb;
        size_t rbq = (size_t)y * WW + c0;
        f4 i0 = *(const f4*)(Ib + rbq);
        f4 i1 = *(const f4*)(Ib + (size_t)HH * WW + rbq);
        f4 i2 = *(const f4*)(Ib + (size_t)2 * HH * WW + rbq);
        if (upd) {
            int ra = refl(y + 1 + RR, HH);
            int rs = refl(y - RR, HH);
            size_t rba = (size_t)ra * WW + c0;
            size_t rbs = (size_t)rs * WW + c0;
            aa0 = *(const f4*)(A0p + rba);
            aa1 = *(const f4*)(A1p + rba);
            aa2 = *(const f4*)(A2p + rba);
            ab  = *(const f4*)(Bp + rba);
            sa0 = *(const f4*)(A0p + rbs);
            sa1 = *(const f4*)(A1p + rbs);
            sa2 = *(const f4*)(A2p + rbs);
            sb  = *(const f4*)(Bp + rbs);
        }
        __syncthreads();

        f4 m[NCH2];
        #pragma unroll
        for (int ch = 0; ch < NCH2; ++ch) {
            float vv[20];
            #pragma unroll
            for (int k = 0; k < 5; ++k)
                ((f4*)vv)[k] = *(const f4*)&lds[ch][c0 + 4 * k];
            float s = (((vv[0]+vv[1])+(vv[2]+vv[3])) + ((vv[4]+vv[5])+(vv[6]+vv[7])))
                    + (((vv[8]+vv[9])+(vv[10]+vv[11])) + ((vv[12]+vv[13])+(vv[14]+vv[15])))
                    + vv[16];
            f4 mm;
            mm[0] = s;
            s += vv[17] - vv[0]; mm[1] = s;
            s += vv[18] - vv[1]; mm[2] = s;
            s += vv[19] - vv[2]; mm[3] = s;
            m[ch] = mm * INV_AREA;
        }

        f4 qv = m[0] * i0 + m[1] * i1 + m[2] * i2 + m[3];
        *(f4*)(Q + (size_t)bz * HH * WW + (size_t)y * WW + c0) = qv;
        __syncthreads();

        if (upd) {
            vs[0] += aa0 - sa0;
            vs[1] += aa1 - sa1;
            vs[2] += aa2 - sa2;
            vs[3] += ab - sb;
        }
    }
}

extern "C" void kernel_launch(void* const* d_in, const int* in_sizes, int n_in,
                              void* d_out, int out_size, void* d_ws, size_t ws_size,
                              hipStream_t stream) {
    const float* I = (const float*)d_in[0];
    const float* P = (const float*)d_in[1];
    float* Q = (float*)d_out;
    float* A = (float*)d_ws;                          // B*3*H*W floats
    float* Bc = A + (size_t)NB * 3 * HH * WW;         // B*H*W floats
    dim3 grid(HH / VSEG, NB);
    gf_stage1<<<grid, 256, 0, stream>>>(I, P, A, Bc);
    gf_stage2<<<grid, 256, 0, stream>>>(I, A, Bc, Q);
}